// Round 1
// baseline (363.992 us; speedup 1.0000x reference)
//
#include <hip/hip_runtime.h>

typedef unsigned short u16;
typedef short bh8 __attribute__((ext_vector_type(8)));
typedef short bh4 __attribute__((ext_vector_type(4)));
typedef float f4 __attribute__((ext_vector_type(4)));
typedef u16 u16x4 __attribute__((ext_vector_type(4)));

// ---------- helpers ----------
__device__ __forceinline__ u16 f2bf(float f) {
  union { float f; unsigned u; } v; v.f = f;
  unsigned u = v.u;
  return (u16)((u + 0x7fffu + ((u >> 16) & 1u)) >> 16);   // RNE, finite inputs
}
__device__ __forceinline__ float bf2f(u16 h) {
  union { unsigned u; float f; } v; v.u = ((unsigned)h) << 16;
  return v.f;
}
__device__ __forceinline__ void gll16(const void* src, void* dst) {
  __builtin_amdgcn_global_load_lds((const __attribute__((address_space(1))) void*)src,
                                   (__attribute__((address_space(3))) void*)dst,
                                   16, 0, 0);
}

// ---------- f32 -> bf16 convert ----------
__global__ __launch_bounds__(256) void k_cvt(const float* __restrict__ in,
                                             u16* __restrict__ out, int n4) {
  int i = blockIdx.x * 256 + threadIdx.x;
  if (i >= n4) return;
  f4 v = *(const f4*)(in + (size_t)i * 4);
  u16x4 o;
  o.x = f2bf(v[0]); o.y = f2bf(v[1]); o.z = f2bf(v[2]); o.w = f2bf(v[3]);
  *(u16x4*)(out + (size_t)i * 4) = o;
}

// ---------- m97-recipe NT GEMM: C[M,N] = A[M,K] * B[N,K]^T ----------
// 128x128 tile, BK=32, 4 waves (2x2), 4x4 16x16x32 bf16 MFMA per wave.
template<int K, bool OUTF32>
__global__ __launch_bounds__(256) void k_gemm(const u16* __restrict__ A,
                                              const u16* __restrict__ B,
                                              void* __restrict__ C, int N) {
  __shared__ u16 As[128 * 32];
  __shared__ u16 Bs[128 * 32];
  const int t = threadIdx.x;
  const int lane = t & 63;
  const int w = t >> 6, wm = w >> 1, wn = w & 1;
  const int g = lane >> 4, r16 = lane & 15;
  const int bm = blockIdx.x, bn = blockIdx.y;

  f4 acc[4][4] = {};

  const int ch0 = t, ch1 = t + 256;
  const int rA0 = ch0 >> 2, cA0 = (ch0 & 3) * 8;
  const int rA1 = ch1 >> 2, cA1 = (ch1 & 3) * 8;
  const u16* a0 = A + (size_t)(bm * 128 + rA0) * K + cA0;
  const u16* a1 = A + (size_t)(bm * 128 + rA1) * K + cA1;
  const u16* b0 = B + (size_t)(bn * 128 + rA0) * K + cA0;
  const u16* b1 = B + (size_t)(bn * 128 + rA1) * K + cA1;

  for (int k0 = 0; k0 < K; k0 += 32) {
    __syncthreads();
    gll16(a0 + k0, As + ch0 * 8);
    gll16(a1 + k0, As + ch1 * 8);
    gll16(b0 + k0, Bs + ch0 * 8);
    gll16(b1 + k0, Bs + ch1 * 8);
    __syncthreads();
    bh8 af[4], bfr[4];
#pragma unroll
    for (int m = 0; m < 4; ++m)
      af[m] = *(const bh8*)&As[(wm * 64 + m * 16 + r16) * 32 + g * 8];
#pragma unroll
    for (int n = 0; n < 4; ++n)
      bfr[n] = *(const bh8*)&Bs[(wn * 64 + n * 16 + r16) * 32 + g * 8];
#pragma unroll
    for (int m = 0; m < 4; ++m)
#pragma unroll
      for (int n = 0; n < 4; ++n)
        acc[m][n] = __builtin_amdgcn_mfma_f32_16x16x32_bf16(af[m], bfr[n], acc[m][n], 0, 0, 0);
  }

#pragma unroll
  for (int m = 0; m < 4; ++m) {
    const int row0 = bm * 128 + wm * 64 + m * 16 + g * 4;
#pragma unroll
    for (int n = 0; n < 4; ++n) {
      const int col = bn * 128 + wn * 64 + n * 16 + r16;
#pragma unroll
      for (int r = 0; r < 4; ++r) {
        if constexpr (OUTF32)
          ((float*)C)[(size_t)(row0 + r) * N + col] = acc[m][n][r];
        else
          ((u16*)C)[(size_t)(row0 + r) * N + col] = f2bf(acc[m][n][r]);
      }
    }
  }
}

// ---------- fused RMSNorm + RoPE (in-place on bf16 Q / K buffers) ----------
// one wave per (seq, head) row of 128; lane holds d=lane and d=lane+64 (rope pair)
__global__ __launch_bounds__(256) void k_normrope(u16* __restrict__ qbuf,
                                                  u16* __restrict__ kvbuf,
                                                  const float* __restrict__ qw,
                                                  const float* __restrict__ kw,
                                                  const float* __restrict__ cosb,
                                                  const float* __restrict__ sinb) {
  const int t = threadIdx.x, lane = t & 63, w = t >> 6;
  const int rid = blockIdx.x * 4 + w;
  u16* base; const float* nw; int seq;
  if (rid < 2048 * 32) {
    seq = rid >> 5;
    base = qbuf + (size_t)seq * 4096 + (size_t)(rid & 31) * 128;
    nw = qw;
  } else {
    const int r2 = rid - 2048 * 32;
    seq = r2 >> 2;
    base = kvbuf + (size_t)seq * 1024 + (size_t)(r2 & 3) * 128;  // K part of fused KV buf
    nw = kw;
  }
  float a = bf2f(base[lane]);
  float b = bf2f(base[lane + 64]);
  float ss = a * a + b * b;
#pragma unroll
  for (int off = 32; off >= 1; off >>= 1) ss += __shfl_xor(ss, off);
  const float rs = rsqrtf(ss * (1.0f / 128.0f) + 1e-6f);
  const float na = a * rs * nw[lane];
  const float nb = b * rs * nw[lane + 64];
  const float c1 = cosb[seq * 128 + lane],      s1 = sinb[seq * 128 + lane];
  const float c2 = cosb[seq * 128 + lane + 64], s2 = sinb[seq * 128 + lane + 64];
  base[lane]      = f2bf(c1 * na - s1 * nb);   // rotate_half: d<64 -> -t[d+64]
  base[lane + 64] = f2bf(c2 * nb + s2 * na);   //              d>=64 ->  t[d-64]
}

// ---------- V transpose: kv[:,512+hd] -> vt[hd][l] ----------
__global__ __launch_bounds__(256) void k_transpose_v(const u16* __restrict__ kv,
                                                     u16* __restrict__ vt) {
  __shared__ u16 tile[32][33];
  const int t = threadIdx.x;
  const int bl = blockIdx.x, bh = blockIdx.y;
  const int row = t >> 3, c4 = (t & 7) * 4;
  const u16* src = kv + (size_t)(bl * 32 + row) * 1024 + 512 + bh * 32 + c4;
  u16x4 v = *(const u16x4*)src;
  tile[row][c4 + 0] = v.x; tile[row][c4 + 1] = v.y;
  tile[row][c4 + 2] = v.z; tile[row][c4 + 3] = v.w;
  __syncthreads();
  u16x4 o;
  o.x = tile[c4 + 0][row]; o.y = tile[c4 + 1][row];
  o.z = tile[c4 + 2][row]; o.w = tile[c4 + 3][row];
  *(u16x4*)&vt[(size_t)(bh * 32 + row) * 2048 + bl * 32 + c4] = o;
}

// ---------- flash attention ----------
// block = 4 waves, 64 q-rows (16 per wave), k-tiles of 64.  Swapped QK^T:
// S^T = mfma(K, Q) so lane holds P^T[key=g*4+r][q=r16] == exact PV B-fragment.
// Q/K LDS tiles 16B-slot XOR-swizzled (slot ^ row&15); Vt tile (slot ^ row&7).
__global__ __launch_bounds__(256) void k_attn(const u16* __restrict__ Q,
                                              const u16* __restrict__ Kb,
                                              const u16* __restrict__ Vt,
                                              u16* __restrict__ O) {
  __shared__ u16 Qs[64 * 128];
  __shared__ u16 Ks[64 * 128];
  __shared__ u16 Vs[128 * 64];
  const int t = threadIdx.x, lane = t & 63, w = t >> 6;
  const int g = lane >> 4, r16 = lane & 15;
  const int qb = blockIdx.x, h = blockIdx.y, kvh = h >> 3;

#pragma unroll
  for (int i = 0; i < 4; ++i) {
    const int s = t + 256 * i, row = s >> 4, sl = s & 15;
    gll16(Q + (size_t)(qb * 64 + row) * 4096 + h * 128 + ((sl ^ (row & 15)) * 8),
          Qs + s * 8);
  }
  __syncthreads();
  bh8 qf[4];
  const int qrow = w * 16 + r16;
#pragma unroll
  for (int kc = 0; kc < 4; ++kc)
    qf[kc] = *(const bh8*)&Qs[qrow * 128 + (((kc * 4 + g) ^ (qrow & 15)) * 8)];

  f4 acc_o[8] = {};
  float mrun = -3.0e38f, lsum = 0.0f;
  const float csc = 1.4426950408889634f * 0.088388347648318447f;  // log2(e)/sqrt(128)
  const int qg = qb * 64 + w * 16 + r16;

  for (int kt = 0; kt <= qb; ++kt) {
    __syncthreads();
#pragma unroll
    for (int i = 0; i < 4; ++i) {
      const int s = t + 256 * i, row = s >> 4, sl = s & 15;
      gll16(Kb + (size_t)(kt * 64 + row) * 1024 + kvh * 128 + ((sl ^ (row & 15)) * 8),
            Ks + s * 8);
    }
#pragma unroll
    for (int i = 0; i < 4; ++i) {
      const int s = t + 256 * i, row = s >> 3, sl = s & 7;
      gll16(Vt + (size_t)(kvh * 128 + row) * 2048 + kt * 64 + ((sl ^ (row & 7)) * 8),
            Vs + s * 8);
    }
    __syncthreads();

    f4 st[4] = {};
#pragma unroll
    for (int kf = 0; kf < 4; ++kf) {
      const int krow = kf * 16 + r16;
#pragma unroll
      for (int kc = 0; kc < 4; ++kc) {
        bh8 kfr = *(const bh8*)&Ks[krow * 128 + (((kc * 4 + g) ^ (krow & 15)) * 8)];
        st[kf] = __builtin_amdgcn_mfma_f32_16x16x32_bf16(kfr, qf[kc], st[kf], 0, 0, 0);
      }
    }

    float s2[16];
    float tmax = -3.0e38f;
    const bool edge = (kt == qb);
#pragma unroll
    for (int kf = 0; kf < 4; ++kf)
#pragma unroll
      for (int r = 0; r < 4; ++r) {
        float v = st[kf][r] * csc;
        if (edge && (kt * 64 + kf * 16 + g * 4 + r) > qg) v = -3.0e38f;
        s2[kf * 4 + r] = v;
        tmax = fmaxf(tmax, v);
      }
    tmax = fmaxf(tmax, __shfl_xor(tmax, 16));
    tmax = fmaxf(tmax, __shfl_xor(tmax, 32));
    const float mnew = fmaxf(mrun, tmax);
    const float alpha = exp2f(mrun - mnew);
    mrun = mnew;
    float psum = 0.0f;
    bh4 pb[4];
#pragma unroll
    for (int kf = 0; kf < 4; ++kf)
#pragma unroll
      for (int r = 0; r < 4; ++r) {
        float p = exp2f(s2[kf * 4 + r] - mnew);
        psum += p;
        pb[kf][r] = (short)f2bf(p);
      }
    psum += __shfl_xor(psum, 16);
    psum += __shfl_xor(psum, 32);
    lsum = lsum * alpha + psum;
#pragma unroll
    for (int d = 0; d < 8; ++d) acc_o[d] *= alpha;

    // O^T += V^T * P^T  (16x16x16, A = V^T frag from Vt tile, B = in-register P^T)
#pragma unroll
    for (int dcol = 0; dcol < 8; ++dcol) {
      const int vrow = dcol * 16 + r16;
#pragma unroll
      for (int kf = 0; kf < 4; ++kf) {
        const int slot = kf * 2 + (g >> 1);
        bh4 vfr = *(const bh4*)&Vs[vrow * 64 + ((slot ^ (vrow & 7)) * 8) + (g & 1) * 4];
        acc_o[dcol] = __builtin_amdgcn_mfma_f32_16x16x16bf16_1k(vfr, pb[kf], acc_o[dcol], 0, 0, 0);
      }
    }
  }

  const float inv = 1.0f / lsum;
#pragma unroll
  for (int dcol = 0; dcol < 8; ++dcol) {
    u16x4 o;
    o.x = f2bf(acc_o[dcol][0] * inv);
    o.y = f2bf(acc_o[dcol][1] * inv);
    o.z = f2bf(acc_o[dcol][2] * inv);
    o.w = f2bf(acc_o[dcol][3] * inv);
    *(u16x4*)&O[(size_t)qg * 4096 + h * 128 + dcol * 16 + g * 4] = o;
  }
}

// ---------- launch ----------
extern "C" void kernel_launch(void* const* d_in, const int* in_sizes, int n_in,
                              void* d_out, int out_size, void* d_ws, size_t ws_size,
                              hipStream_t stream) {
  (void)in_sizes; (void)n_in; (void)out_size; (void)ws_size;
  const float* x    = (const float*)d_in[0];
  const float* wq   = (const float*)d_in[1];
  const float* wk   = (const float*)d_in[2];
  const float* wv   = (const float*)d_in[3];
  const float* wo   = (const float*)d_in[4];
  const float* qw   = (const float*)d_in[5];
  const float* kw   = (const float*)d_in[6];
  const float* cosb = (const float*)d_in[7];
  const float* sinb = (const float*)d_in[8];

  // ws layout (bf16 elements), ~66 MB total
  u16* xb   = (u16*)d_ws;                    // x bf16 [2048][2048]; reused as attn_out [2048][4096]... separate: see aout
  u16* wqb  = xb  + (size_t)2048 * 2048;     // [4096][2048]
  u16* wkvb = wqb + (size_t)4096 * 2048;     // [1024][2048]  (wk rows 0..511, wv rows 512..1023)
  u16* wob  = wkvb + (size_t)1024 * 2048;    // [2048][4096]
  u16* qbuf = wob + (size_t)2048 * 4096;     // [2048][4096]  q proj, normed+roped in place
  u16* kvb  = qbuf + (size_t)2048 * 4096;    // [2048][1024]  cols 0..511 K, 512..1023 V
  u16* vt   = kvb + (size_t)2048 * 1024;     // [512][2048]   V^T
  u16* aout = vt  + (size_t)512 * 2048;      // [2048][4096]  attention output

  // 1. converts
  k_cvt<<<dim3(4096), 256, 0, stream>>>(x,  xb,   2048 * 2048 / 4);
  k_cvt<<<dim3(8192), 256, 0, stream>>>(wq, wqb,  4096 * 2048 / 4);
  k_cvt<<<dim3(1024), 256, 0, stream>>>(wk, wkvb,                     512 * 2048 / 4);
  k_cvt<<<dim3(1024), 256, 0, stream>>>(wv, wkvb + (size_t)512 * 2048, 512 * 2048 / 4);
  k_cvt<<<dim3(8192), 256, 0, stream>>>(wo, wob,  2048 * 4096 / 4);

  // 2. projections
  k_gemm<2048, false><<<dim3(16, 32), 256, 0, stream>>>(xb, wqb,  qbuf, 4096);
  k_gemm<2048, false><<<dim3(16, 8),  256, 0, stream>>>(xb, wkvb, kvb,  1024);

  // 3. rmsnorm + rope (q rows then k rows), 4 rows per block
  k_normrope<<<dim3((2048 * 36) / 4), 256, 0, stream>>>(qbuf, kvb, qw, kw, cosb, sinb);

  // 4. V transpose
  k_transpose_v<<<dim3(64, 16), 256, 0, stream>>>(kvb, vt);

  // 5. flash attention
  k_attn<<<dim3(32, 32), 256, 0, stream>>>(qbuf, kvb, vt, aout);

  // 6. output projection (f32 out)
  k_gemm<4096, true><<<dim3(16, 16), 256, 0, stream>>>(aout, wob, d_out, 2048);
}

// Round 2
// 257.090 us; speedup vs baseline: 1.4158x; 1.4158x over previous
//
#include <hip/hip_runtime.h>

typedef unsigned short u16;
typedef short bh8 __attribute__((ext_vector_type(8)));
typedef short bh4 __attribute__((ext_vector_type(4)));
typedef float f4 __attribute__((ext_vector_type(4)));
typedef u16 u16x4 __attribute__((ext_vector_type(4)));

// ---------- helpers ----------
__device__ __forceinline__ u16 f2bf(float f) {
  union { float f; unsigned u; } v; v.f = f;
  unsigned u = v.u;
  return (u16)((u + 0x7fffu + ((u >> 16) & 1u)) >> 16);   // RNE, finite inputs
}
__device__ __forceinline__ float bf2f(u16 h) {
  union { unsigned u; float f; } v; v.u = ((unsigned)h) << 16;
  return v.f;
}
__device__ __forceinline__ void gll16(const void* src, void* dst) {
  __builtin_amdgcn_global_load_lds((const __attribute__((address_space(1))) void*)src,
                                   (__attribute__((address_space(3))) void*)dst,
                                   16, 0, 0);
}

// ---------- f32 -> bf16 convert ----------
__global__ __launch_bounds__(256) void k_cvt(const float* __restrict__ in,
                                             u16* __restrict__ out, int n4) {
  int i = blockIdx.x * 256 + threadIdx.x;
  if (i >= n4) return;
  f4 v = *(const f4*)(in + (size_t)i * 4);
  u16x4 o;
  o.x = f2bf(v[0]); o.y = f2bf(v[1]); o.z = f2bf(v[2]); o.w = f2bf(v[3]);
  *(u16x4*)(out + (size_t)i * 4) = o;
}

// ---------- NT GEMM: C[M,N] = A[M,K] * B[N,K]^T ----------
// 128xBN tile (BN = NFR*32), BK=32, 4 waves (2x2), 4xNFR 16x16x32 bf16 MFMA/wave.
// FUSED: blockIdx.y < NB1 -> (B1,C1,N1), else (B2,C2,N2) with local bn.
template<int K, bool OUTF32, int NFR, bool FUSED>
__global__ __launch_bounds__(256) void k_gemm(const u16* __restrict__ A,
                                              const u16* __restrict__ B1,
                                              const u16* __restrict__ B2,
                                              void* __restrict__ C1,
                                              void* __restrict__ C2,
                                              int N1, int N2, int NB1) {
  constexpr int BN = NFR * 32;
  __shared__ u16 As[128 * 32];
  __shared__ u16 Bs[BN * 32];
  const int t = threadIdx.x;
  const int lane = t & 63;
  const int w = t >> 6, wm = w >> 1, wn = w & 1;
  const int g = lane >> 4, r16 = lane & 15;
  const int bm = blockIdx.x;
  int bn = blockIdx.y;

  const u16* B; void* C; int N;
  if (!FUSED || bn < NB1) { B = B1; C = C1; N = N1; }
  else { bn -= NB1; B = B2; C = C2; N = N2; }
  B += (size_t)bn * BN * K;

  f4 acc[4][NFR] = {};

  const int rA0 = t >> 2, cA0 = (t & 3) * 8;
  const u16* a0 = A + (size_t)(bm * 128 + rA0) * K + cA0;
  const u16* a1 = a0 + (size_t)64 * K;
  const u16* b0 = B + (size_t)rA0 * K + cA0;

  for (int k0 = 0; k0 < K; k0 += 32) {
    __syncthreads();
    gll16(a0 + k0, As + t * 8);
    gll16(a1 + k0, As + (t + 256) * 8);
    gll16(b0 + k0, Bs + t * 8);
    if (BN == 128) gll16(b0 + (size_t)64 * K + k0, Bs + (t + 256) * 8);
    __syncthreads();
    bh8 af[4], bfr[NFR];
#pragma unroll
    for (int m = 0; m < 4; ++m)
      af[m] = *(const bh8*)&As[(wm * 64 + m * 16 + r16) * 32 + g * 8];
#pragma unroll
    for (int n = 0; n < NFR; ++n)
      bfr[n] = *(const bh8*)&Bs[(wn * 16 * NFR + n * 16 + r16) * 32 + g * 8];
    __builtin_amdgcn_s_setprio(1);
#pragma unroll
    for (int m = 0; m < 4; ++m)
#pragma unroll
      for (int n = 0; n < NFR; ++n)
        acc[m][n] = __builtin_amdgcn_mfma_f32_16x16x32_bf16(af[m], bfr[n], acc[m][n], 0, 0, 0);
    __builtin_amdgcn_s_setprio(0);
  }

#pragma unroll
  for (int m = 0; m < 4; ++m) {
    const int row0 = bm * 128 + wm * 64 + m * 16 + g * 4;
#pragma unroll
    for (int n = 0; n < NFR; ++n) {
      const int col = bn * BN + wn * 16 * NFR + n * 16 + r16;
#pragma unroll
      for (int r = 0; r < 4; ++r) {
        if constexpr (OUTF32)
          ((float*)C)[(size_t)(row0 + r) * N + col] = acc[m][n][r];
        else
          ((u16*)C)[(size_t)(row0 + r) * N + col] = f2bf(acc[m][n][r]);
      }
    }
  }
}

// ---------- fused RMSNorm + RoPE (in-place on bf16 Q / K buffers) ----------
__global__ __launch_bounds__(256) void k_normrope(u16* __restrict__ qbuf,
                                                  u16* __restrict__ kvbuf,
                                                  const float* __restrict__ qw,
                                                  const float* __restrict__ kw,
                                                  const float* __restrict__ cosb,
                                                  const float* __restrict__ sinb) {
  const int t = threadIdx.x, lane = t & 63, w = t >> 6;
  const int rid = blockIdx.x * 4 + w;
  u16* base; const float* nw; int seq;
  if (rid < 2048 * 32) {
    seq = rid >> 5;
    base = qbuf + (size_t)seq * 4096 + (size_t)(rid & 31) * 128;
    nw = qw;
  } else {
    const int r2 = rid - 2048 * 32;
    seq = r2 >> 2;
    base = kvbuf + (size_t)seq * 1024 + (size_t)(r2 & 3) * 128;
    nw = kw;
  }
  float a = bf2f(base[lane]);
  float b = bf2f(base[lane + 64]);
  float ss = a * a + b * b;
#pragma unroll
  for (int off = 32; off >= 1; off >>= 1) ss += __shfl_xor(ss, off);
  const float rs = rsqrtf(ss * (1.0f / 128.0f) + 1e-6f);
  const float na = a * rs * nw[lane];
  const float nb = b * rs * nw[lane + 64];
  const float c1 = cosb[seq * 128 + lane],      s1 = sinb[seq * 128 + lane];
  const float c2 = cosb[seq * 128 + lane + 64], s2 = sinb[seq * 128 + lane + 64];
  base[lane]      = f2bf(c1 * na - s1 * nb);
  base[lane + 64] = f2bf(c2 * nb + s2 * na);
}

// ---------- V transpose: kv[:,512+hd] -> vt[hd][l] ----------
__global__ __launch_bounds__(256) void k_transpose_v(const u16* __restrict__ kv,
                                                     u16* __restrict__ vt) {
  __shared__ u16 tile[32][33];
  const int t = threadIdx.x;
  const int bl = blockIdx.x, bh = blockIdx.y;
  const int row = t >> 3, c4 = (t & 7) * 4;
  const u16* src = kv + (size_t)(bl * 32 + row) * 1024 + 512 + bh * 32 + c4;
  u16x4 v = *(const u16x4*)src;
  tile[row][c4 + 0] = v.x; tile[row][c4 + 1] = v.y;
  tile[row][c4 + 2] = v.z; tile[row][c4 + 3] = v.w;
  __syncthreads();
  u16x4 o;
  o.x = tile[c4 + 0][row]; o.y = tile[c4 + 1][row];
  o.z = tile[c4 + 2][row]; o.w = tile[c4 + 3][row];
  *(u16x4*)&vt[(size_t)(bh * 32 + row) * 2048 + bl * 32 + c4] = o;
}

// ---------- flash attention ----------
// 8 waves, 128 q-rows/block (16/wave), k-tiles of 64, double-buffered K/V with
// 2-phase prefetch.  Swapped QK^T: S^T = mfma(K, Q) so lane's P^T == PV B-frag.
// Work-paired dispatch: block i and i+256 land on same CU with complementary qb.
__global__ __launch_bounds__(512, 4) void k_attn(const u16* __restrict__ Q,
                                                 const u16* __restrict__ Kb,
                                                 const u16* __restrict__ Vt,
                                                 u16* __restrict__ O) {
  __shared__ u16 Ks[2][64 * 128];
  __shared__ u16 Vs[2][128 * 64];
  const int t = threadIdx.x, lane = t & 63, w = t >> 6;
  const int g = lane >> 4, r16 = lane & 15;
  const int j = blockIdx.x >> 5, h = blockIdx.x & 31;
  const int qb = (j < 8) ? (15 - j) : (j - 8);   // pair big+small on same CU
  const int kvh = h >> 3;
  const int qw0 = qb * 128 + w * 16;             // wave's first q row
  const int qg  = qw0 + r16;                     // lane's q row

  // Q fragments straight from global (L2-resident)
  bh8 qf[4];
#pragma unroll
  for (int kc = 0; kc < 4; ++kc)
    qf[kc] = *(const bh8*)(Q + (size_t)qg * 4096 + h * 128 + (kc * 4 + g) * 8);

  const int niter = 2 * qb + 2;

  f4 acc_o[8] = {};
  float mrun = -3.0e38f, lsum = 0.0f;
  const float csc = 1.4426950408889634f * 0.088388347648318447f;  // log2(e)/sqrt(128)

  // prologue stage tile 0 into buf 0
  {
#pragma unroll
    for (int i = 0; i < 2; ++i) {
      const int s = t + 512 * i, row = s >> 4, sl = s & 15;
      gll16(Kb + (size_t)row * 1024 + kvh * 128 + ((sl ^ (row & 15)) * 8), Ks[0] + s * 8);
    }
#pragma unroll
    for (int i = 0; i < 2; ++i) {
      const int s = t + 512 * i, row = s >> 3, sl = s & 7;
      gll16(Vt + (size_t)(kvh * 128 + row) * 2048 + ((sl ^ (row & 7)) * 8), Vs[0] + s * 8);
    }
  }
  __syncthreads();

  int cur = 0;
  for (int kt = 0; kt < niter; ++kt) {
    // prefetch next tile into the other buffer (no wait here)
    if (kt + 1 < niter) {
      const int nt = kt + 1;
#pragma unroll
      for (int i = 0; i < 2; ++i) {
        const int s = t + 512 * i, row = s >> 4, sl = s & 15;
        gll16(Kb + (size_t)(nt * 64 + row) * 1024 + kvh * 128 + ((sl ^ (row & 15)) * 8),
              Ks[cur ^ 1] + s * 8);
      }
#pragma unroll
      for (int i = 0; i < 2; ++i) {
        const int s = t + 512 * i, row = s >> 3, sl = s & 7;
        gll16(Vt + (size_t)(kvh * 128 + row) * 2048 + nt * 64 + ((sl ^ (row & 7)) * 8),
              Vs[cur ^ 1] + s * 8);
      }
    }

    const bool active = (kt * 64 <= qw0 + 15);
    if (active) {
      // QK^T (swapped operands -> S^T)
      f4 st[4] = {};
      __builtin_amdgcn_s_setprio(1);
#pragma unroll
      for (int kf = 0; kf < 4; ++kf) {
        const int krow = kf * 16 + r16;
#pragma unroll
        for (int kc = 0; kc < 4; ++kc) {
          bh8 kfr = *(const bh8*)&Ks[cur][krow * 128 + (((kc * 4 + g) ^ (krow & 15)) * 8)];
          st[kf] = __builtin_amdgcn_mfma_f32_16x16x32_bf16(kfr, qf[kc], st[kf], 0, 0, 0);
        }
      }
      __builtin_amdgcn_s_setprio(0);

      // scale + causal mask + row max (in place in st)
      float tmax = -3.0e38f;
      const bool edge = ((kt + 1) * 64 - 1 > qw0);
#pragma unroll
      for (int kf = 0; kf < 4; ++kf)
#pragma unroll
        for (int r = 0; r < 4; ++r) {
          float v = st[kf][r] * csc;
          if (edge && (kt * 64 + kf * 16 + g * 4 + r) > qg) v = -3.0e38f;
          st[kf][r] = v;
          tmax = fmaxf(tmax, v);
        }
      tmax = fmaxf(tmax, __shfl_xor(tmax, 16));
      tmax = fmaxf(tmax, __shfl_xor(tmax, 32));

      // defer-max (T13): only rescale when the running max grew materially
      if (!__all(tmax <= mrun + 8.0f)) {
        const float mnew = fmaxf(mrun, tmax);
        const float alpha = exp2f(mrun - mnew);
        mrun = mnew;
        lsum *= alpha;
#pragma unroll
        for (int d = 0; d < 8; ++d) acc_o[d] *= alpha;
      }

      float psum = 0.0f;
      bh4 pb[4];
#pragma unroll
      for (int kf = 0; kf < 4; ++kf)
#pragma unroll
        for (int r = 0; r < 4; ++r) {
          float p = exp2f(st[kf][r] - mrun);
          psum += p;
          pb[kf][r] = (short)f2bf(p);
        }
      psum += __shfl_xor(psum, 16);
      psum += __shfl_xor(psum, 32);
      lsum += psum;

      // O^T += V^T * P^T
      __builtin_amdgcn_s_setprio(1);
#pragma unroll
      for (int dcol = 0; dcol < 8; ++dcol) {
        const int vrow = dcol * 16 + r16;
#pragma unroll
        for (int kf = 0; kf < 4; ++kf) {
          const int slot = kf * 2 + (g >> 1);
          bh4 vfr = *(const bh4*)&Vs[cur][vrow * 64 + ((slot ^ (vrow & 7)) * 8) + (g & 1) * 4];
          acc_o[dcol] = __builtin_amdgcn_mfma_f32_16x16x16bf16_1k(vfr, pb[kf], acc_o[dcol], 0, 0, 0);
        }
      }
      __builtin_amdgcn_s_setprio(0);
    }

    __syncthreads();   // drains prefetch (vmcnt) + all reads of buf[cur]
    cur ^= 1;
  }

  const float inv = 1.0f / lsum;
#pragma unroll
  for (int dcol = 0; dcol < 8; ++dcol) {
    u16x4 o;
    o.x = f2bf(acc_o[dcol][0] * inv);
    o.y = f2bf(acc_o[dcol][1] * inv);
    o.z = f2bf(acc_o[dcol][2] * inv);
    o.w = f2bf(acc_o[dcol][3] * inv);
    *(u16x4*)&O[(size_t)qg * 4096 + h * 128 + dcol * 16 + g * 4] = o;
  }
}

// ---------- launch ----------
extern "C" void kernel_launch(void* const* d_in, const int* in_sizes, int n_in,
                              void* d_out, int out_size, void* d_ws, size_t ws_size,
                              hipStream_t stream) {
  (void)in_sizes; (void)n_in; (void)out_size; (void)ws_size;
  const float* x    = (const float*)d_in[0];
  const float* wq   = (const float*)d_in[1];
  const float* wk   = (const float*)d_in[2];
  const float* wv   = (const float*)d_in[3];
  const float* wo   = (const float*)d_in[4];
  const float* qw   = (const float*)d_in[5];
  const float* kw   = (const float*)d_in[6];
  const float* cosb = (const float*)d_in[7];
  const float* sinb = (const float*)d_in[8];

  u16* xb   = (u16*)d_ws;                    // [2048][2048]
  u16* wqb  = xb  + (size_t)2048 * 2048;     // [4096][2048]
  u16* wkvb = wqb + (size_t)4096 * 2048;     // [1024][2048]
  u16* wob  = wkvb + (size_t)1024 * 2048;    // [2048][4096]
  u16* qbuf = wob + (size_t)2048 * 4096;     // [2048][4096]
  u16* kvb  = qbuf + (size_t)2048 * 4096;    // [2048][1024]
  u16* vt   = kvb + (size_t)2048 * 1024;     // [512][2048]
  u16* aout = vt  + (size_t)512 * 2048;      // [2048][4096]

  // 1. converts
  k_cvt<<<dim3(4096), 256, 0, stream>>>(x,  xb,   2048 * 2048 / 4);
  k_cvt<<<dim3(8192), 256, 0, stream>>>(wq, wqb,  4096 * 2048 / 4);
  k_cvt<<<dim3(1024), 256, 0, stream>>>(wk, wkvb,                      512 * 2048 / 4);
  k_cvt<<<dim3(1024), 256, 0, stream>>>(wv, wkvb + (size_t)512 * 2048, 512 * 2048 / 4);
  k_cvt<<<dim3(8192), 256, 0, stream>>>(wo, wob,  2048 * 4096 / 4);

  // 2. fused Q + KV projection (one launch, 640 blocks)
  k_gemm<2048, false, 4, true><<<dim3(16, 40), 256, 0, stream>>>(
      xb, wqb, wkvb, qbuf, kvb, 4096, 1024, 32);

  // 3. rmsnorm + rope
  k_normrope<<<dim3((2048 * 36) / 4), 256, 0, stream>>>(qbuf, kvb, qw, kw, cosb, sinb);

  // 4. V transpose
  k_transpose_v<<<dim3(64, 16), 256, 0, stream>>>(kvb, vt);

  // 5. flash attention (512 paired blocks)
  k_attn<<<dim3(512), 512, 0, stream>>>(qbuf, kvb, vt, aout);

  // 6. output projection, 128x64 tiles -> 512 blocks
  k_gemm<4096, true, 2, false><<<dim3(16, 32), 256, 0, stream>>>(
      aout, wob, nullptr, d_out, nullptr, 2048, 0, 0);
}

// Round 3
// 239.559 us; speedup vs baseline: 1.5194x; 1.0732x over previous
//
#include <hip/hip_runtime.h>

typedef unsigned short u16;
typedef short bh8 __attribute__((ext_vector_type(8)));
typedef short bh4 __attribute__((ext_vector_type(4)));
typedef float f4 __attribute__((ext_vector_type(4)));
typedef u16 u16x4 __attribute__((ext_vector_type(4)));

// ---------- helpers ----------
__device__ __forceinline__ u16 f2bf(float f) {
  union { float f; unsigned u; } v; v.f = f;
  unsigned u = v.u;
  return (u16)((u + 0x7fffu + ((u >> 16) & 1u)) >> 16);   // RNE, finite inputs
}
__device__ __forceinline__ float bf2f(u16 h) {
  union { unsigned u; float f; } v; v.u = ((unsigned)h) << 16;
  return v.f;
}
__device__ __forceinline__ void gll16(const void* src, void* dst) {
  __builtin_amdgcn_global_load_lds((const __attribute__((address_space(1))) void*)src,
                                   (__attribute__((address_space(3))) void*)dst,
                                   16, 0, 0);
}

// ---------- f32 -> bf16 convert ----------
__global__ __launch_bounds__(256) void k_cvt(const float* __restrict__ in,
                                             u16* __restrict__ out, int n4) {
  int i = blockIdx.x * 256 + threadIdx.x;
  if (i >= n4) return;
  f4 v = *(const f4*)(in + (size_t)i * 4);
  u16x4 o;
  o.x = f2bf(v[0]); o.y = f2bf(v[1]); o.z = f2bf(v[2]); o.w = f2bf(v[3]);
  *(u16x4*)(out + (size_t)i * 4) = o;
}

// ---------- NT GEMM, 2-phase dbuf prefetch: C[M,N] = A[M,K] * B[N,K]^T ----------
// 128xBN tile (BN = NFR*32), BK=32, 4 waves (2x2), 4xNFR 16x16x32 bf16 MFMA/wave.
// T3-minimum: stage(next)->ds_read(cur)->MFMA->barrier, 1 barrier/K-step.
template<int K, bool OUTF32, int NFR, bool FUSED>
__global__ __launch_bounds__(256) void k_gemm(const u16* __restrict__ A,
                                              const u16* __restrict__ B1,
                                              const u16* __restrict__ B2,
                                              void* __restrict__ C1,
                                              void* __restrict__ C2,
                                              int N1, int N2, int NB1) {
  constexpr int BN = NFR * 32;
  __shared__ u16 As[2][128 * 32];
  __shared__ u16 Bs[2][BN * 32];
  const int t = threadIdx.x;
  const int lane = t & 63;
  const int w = t >> 6, wm = w >> 1, wn = w & 1;
  const int g = lane >> 4, r16 = lane & 15;
  const int bm = blockIdx.x;
  int bn = blockIdx.y;

  const u16* B; void* C; int N;
  if (!FUSED || bn < NB1) { B = B1; C = C1; N = N1; }
  else { bn -= NB1; B = B2; C = C2; N = N2; }
  B += (size_t)bn * BN * K;

  f4 acc[4][NFR] = {};

  const int rA0 = t >> 2, cA0 = (t & 3) * 8;
  const u16* a0 = A + (size_t)(bm * 128 + rA0) * K + cA0;
  const u16* a1 = a0 + (size_t)64 * K;
  const u16* b0 = B + (size_t)rA0 * K + cA0;

  // prologue: stage tile 0
  gll16(a0, As[0] + t * 8);
  gll16(a1, As[0] + (t + 256) * 8);
  gll16(b0, Bs[0] + t * 8);
  if (BN == 128) gll16(b0 + (size_t)64 * K, Bs[0] + (t + 256) * 8);
  __syncthreads();

  int cur = 0;
  for (int k0 = 0; k0 < K; k0 += 32) {
    // issue next-tile stage into the other buffer (hidden under compute)
    if (k0 + 32 < K) {
      gll16(a0 + k0 + 32, As[cur ^ 1] + t * 8);
      gll16(a1 + k0 + 32, As[cur ^ 1] + (t + 256) * 8);
      gll16(b0 + k0 + 32, Bs[cur ^ 1] + t * 8);
      if (BN == 128) gll16(b0 + (size_t)64 * K + k0 + 32, Bs[cur ^ 1] + (t + 256) * 8);
    }
    bh8 af[4], bfr[NFR];
#pragma unroll
    for (int m = 0; m < 4; ++m)
      af[m] = *(const bh8*)&As[cur][(wm * 64 + m * 16 + r16) * 32 + g * 8];
#pragma unroll
    for (int n = 0; n < NFR; ++n)
      bfr[n] = *(const bh8*)&Bs[cur][(wn * 16 * NFR + n * 16 + r16) * 32 + g * 8];
    __builtin_amdgcn_s_setprio(1);
#pragma unroll
    for (int m = 0; m < 4; ++m)
#pragma unroll
      for (int n = 0; n < NFR; ++n)
        acc[m][n] = __builtin_amdgcn_mfma_f32_16x16x32_bf16(af[m], bfr[n], acc[m][n], 0, 0, 0);
    __builtin_amdgcn_s_setprio(0);
    __syncthreads();   // drains next-tile vmcnt + all ds_reads of buf[cur]
    cur ^= 1;
  }

#pragma unroll
  for (int m = 0; m < 4; ++m) {
    const int row0 = bm * 128 + wm * 64 + m * 16 + g * 4;
#pragma unroll
    for (int n = 0; n < NFR; ++n) {
      const int col = bn * BN + wn * 16 * NFR + n * 16 + r16;
#pragma unroll
      for (int r = 0; r < 4; ++r) {
        if constexpr (OUTF32)
          ((float*)C)[(size_t)(row0 + r) * N + col] = acc[m][n][r];
        else
          ((u16*)C)[(size_t)(row0 + r) * N + col] = f2bf(acc[m][n][r]);
      }
    }
  }
}

// ---------- fused RMSNorm + RoPE (in-place on bf16 Q / K buffers) ----------
// Q rows additionally scaled by log2(e)/sqrt(D) so attention scores come out
// in log2 domain with no per-element scale.
__global__ __launch_bounds__(256) void k_normrope(u16* __restrict__ qbuf,
                                                  u16* __restrict__ kvbuf,
                                                  const float* __restrict__ qw,
                                                  const float* __restrict__ kw,
                                                  const float* __restrict__ cosb,
                                                  const float* __restrict__ sinb) {
  const float CSC = 1.4426950408889634f * 0.088388347648318447f;  // log2(e)/sqrt(128)
  const int t = threadIdx.x, lane = t & 63, w = t >> 6;
  const int rid = blockIdx.x * 4 + w;
  u16* base; const float* nw; int seq; float sc;
  if (rid < 2048 * 32) {
    seq = rid >> 5;
    base = qbuf + (size_t)seq * 4096 + (size_t)(rid & 31) * 128;
    nw = qw; sc = CSC;
  } else {
    const int r2 = rid - 2048 * 32;
    seq = r2 >> 2;
    base = kvbuf + (size_t)seq * 1024 + (size_t)(r2 & 3) * 128;
    nw = kw; sc = 1.0f;
  }
  float a = bf2f(base[lane]);
  float b = bf2f(base[lane + 64]);
  float ss = a * a + b * b;
#pragma unroll
  for (int off = 32; off >= 1; off >>= 1) ss += __shfl_xor(ss, off);
  const float rs = rsqrtf(ss * (1.0f / 128.0f) + 1e-6f);
  const float na = a * rs * nw[lane];
  const float nb = b * rs * nw[lane + 64];
  const float c1 = cosb[seq * 128 + lane],      s1 = sinb[seq * 128 + lane];
  const float c2 = cosb[seq * 128 + lane + 64], s2 = sinb[seq * 128 + lane + 64];
  base[lane]      = f2bf(sc * (c1 * na - s1 * nb));
  base[lane + 64] = f2bf(sc * (c2 * nb + s2 * na));
}

// ---------- V transpose: kv[:,512+hd] -> vt[hd][l], 32-key chunk permuted ----------
// Within each 32-key chunk, key k is stored at slot pi^-1(k) = ((k>>2)&3)*8 +
// (k>>4)*4 + (k&3) so the PV x32 A-fragment k-slot order matches the natural
// P^T (S^T C-layout) order with zero shuffles.
__global__ __launch_bounds__(256) void k_transpose_v(const u16* __restrict__ kv,
                                                     u16* __restrict__ vt) {
  __shared__ u16 tile[32][33];
  const int t = threadIdx.x;
  const int bl = blockIdx.x, bh = blockIdx.y;
  const int row = t >> 3, c4 = (t & 7) * 4;
  const u16* src = kv + (size_t)(bl * 32 + row) * 1024 + 512 + bh * 32 + c4;
  u16x4 v = *(const u16x4*)src;
  tile[row][c4 + 0] = v.x; tile[row][c4 + 1] = v.y;
  tile[row][c4 + 2] = v.z; tile[row][c4 + 3] = v.w;
  __syncthreads();
  u16x4 o;
  o.x = tile[c4 + 0][row]; o.y = tile[c4 + 1][row];
  o.z = tile[c4 + 2][row]; o.w = tile[c4 + 3][row];
  const int pcol = ((c4 >> 2) & 3) * 8 + (c4 >> 4) * 4;   // pi^-1 (keys c4..c4+3 stay contiguous)
  *(u16x4*)&vt[(size_t)(bh * 32 + row) * 2048 + bl * 32 + pcol] = o;
}

// ---------- flash attention ----------
// 8 waves, 128 q-rows/block, k-tiles of 64, double-buffered K/V, 2-phase
// prefetch.  Swapped QK^T: S^T = mfma(K,Q); PV on 16x16x32 with chunk-permuted
// V^T so P^T packs directly into the B-fragment.
__global__ __launch_bounds__(512, 4) void k_attn(const u16* __restrict__ Q,
                                                 const u16* __restrict__ Kb,
                                                 const u16* __restrict__ Vt,
                                                 u16* __restrict__ O) {
  __shared__ u16 Ks[2][64 * 128];
  __shared__ u16 Vs[2][128 * 64];
  const int t = threadIdx.x, lane = t & 63, w = t >> 6;
  const int g = lane >> 4, r16 = lane & 15;
  const int j = blockIdx.x >> 5, h = blockIdx.x & 31;
  const int qb = (j < 8) ? (15 - j) : (j - 8);   // pair big+small on same CU
  const int kvh = h >> 3;
  const int qw0 = qb * 128 + w * 16;
  const int qg  = qw0 + r16;

  bh8 qf[4];
#pragma unroll
  for (int kc = 0; kc < 4; ++kc)
    qf[kc] = *(const bh8*)(Q + (size_t)qg * 4096 + h * 128 + (kc * 4 + g) * 8);

  const int niter = 2 * qb + 2;

  f4 acc_o[8] = {};
  float mrun = -3.0e38f, lsum = 0.0f;

  {
#pragma unroll
    for (int i = 0; i < 2; ++i) {
      const int s = t + 512 * i, row = s >> 4, sl = s & 15;
      gll16(Kb + (size_t)row * 1024 + kvh * 128 + ((sl ^ (row & 15)) * 8), Ks[0] + s * 8);
    }
#pragma unroll
    for (int i = 0; i < 2; ++i) {
      const int s = t + 512 * i, row = s >> 3, sl = s & 7;
      gll16(Vt + (size_t)(kvh * 128 + row) * 2048 + ((sl ^ (row & 7)) * 8), Vs[0] + s * 8);
    }
  }
  __syncthreads();

  int cur = 0;
  for (int kt = 0; kt < niter; ++kt) {
    if (kt + 1 < niter) {
      const int nt = kt + 1;
#pragma unroll
      for (int i = 0; i < 2; ++i) {
        const int s = t + 512 * i, row = s >> 4, sl = s & 15;
        gll16(Kb + (size_t)(nt * 64 + row) * 1024 + kvh * 128 + ((sl ^ (row & 15)) * 8),
              Ks[cur ^ 1] + s * 8);
      }
#pragma unroll
      for (int i = 0; i < 2; ++i) {
        const int s = t + 512 * i, row = s >> 3, sl = s & 7;
        gll16(Vt + (size_t)(kvh * 128 + row) * 2048 + nt * 64 + ((sl ^ (row & 7)) * 8),
              Vs[cur ^ 1] + s * 8);
      }
    }

    const bool active = (kt * 64 <= qw0 + 15);
    if (active) {
      // QK^T (swapped operands -> S^T), scores already in log2 domain
      f4 st[4] = {};
      __builtin_amdgcn_s_setprio(1);
#pragma unroll
      for (int kf = 0; kf < 4; ++kf) {
        const int krow = kf * 16 + r16;
#pragma unroll
        for (int kc = 0; kc < 4; ++kc) {
          bh8 kfr = *(const bh8*)&Ks[cur][krow * 128 + (((kc * 4 + g) ^ (krow & 15)) * 8)];
          st[kf] = __builtin_amdgcn_mfma_f32_16x16x32_bf16(kfr, qf[kc], st[kf], 0, 0, 0);
        }
      }
      __builtin_amdgcn_s_setprio(0);

      float tmax = -3.0e38f;
      const bool edge = ((kt + 1) * 64 - 1 > qw0);
#pragma unroll
      for (int kf = 0; kf < 4; ++kf)
#pragma unroll
        for (int r = 0; r < 4; ++r) {
          float v = st[kf][r];
          if (edge && (kt * 64 + kf * 16 + g * 4 + r) > qg) v = -3.0e38f;
          st[kf][r] = v;
          tmax = fmaxf(tmax, v);
        }
      tmax = fmaxf(tmax, __shfl_xor(tmax, 16));
      tmax = fmaxf(tmax, __shfl_xor(tmax, 32));

      // defer-max (T13)
      if (!__all(tmax <= mrun + 8.0f)) {
        const float mnew = fmaxf(mrun, tmax);
        const float alpha = exp2f(mrun - mnew);
        mrun = mnew;
        lsum *= alpha;
#pragma unroll
        for (int d = 0; d < 8; ++d) acc_o[d] *= alpha;
      }

      float psum = 0.0f;
      bh8 pb2[2];
#pragma unroll
      for (int kf = 0; kf < 4; ++kf)
#pragma unroll
        for (int r = 0; r < 4; ++r) {
          float p = exp2f(st[kf][r] - mrun);
          psum += p;
          pb2[kf >> 1][(kf & 1) * 4 + r] = (short)f2bf(p);
        }
      psum += __shfl_xor(psum, 16);
      psum += __shfl_xor(psum, 32);
      lsum += psum;

      // O^T += V^T * P^T on 16x16x32 (chunk-permuted V^T matches P^T k-slots)
      __builtin_amdgcn_s_setprio(1);
#pragma unroll
      for (int dcol = 0; dcol < 8; ++dcol) {
        const int vrow = dcol * 16 + r16;
#pragma unroll
        for (int c = 0; c < 2; ++c) {
          const int slot = c * 4 + g;
          bh8 vfr = *(const bh8*)&Vs[cur][vrow * 64 + ((slot ^ (vrow & 7)) * 8)];
          acc_o[dcol] = __builtin_amdgcn_mfma_f32_16x16x32_bf16(vfr, pb2[c], acc_o[dcol], 0, 0, 0);
        }
      }
      __builtin_amdgcn_s_setprio(0);
    }

    __syncthreads();
    cur ^= 1;
  }

  const float inv = 1.0f / lsum;
#pragma unroll
  for (int dcol = 0; dcol < 8; ++dcol) {
    u16x4 o;
    o.x = f2bf(acc_o[dcol][0] * inv);
    o.y = f2bf(acc_o[dcol][1] * inv);
    o.z = f2bf(acc_o[dcol][2] * inv);
    o.w = f2bf(acc_o[dcol][3] * inv);
    *(u16x4*)&O[(size_t)qg * 4096 + h * 128 + dcol * 16 + g * 4] = o;
  }
}

// ---------- launch ----------
extern "C" void kernel_launch(void* const* d_in, const int* in_sizes, int n_in,
                              void* d_out, int out_size, void* d_ws, size_t ws_size,
                              hipStream_t stream) {
  (void)in_sizes; (void)n_in; (void)out_size; (void)ws_size;
  const float* x    = (const float*)d_in[0];
  const float* wq   = (const float*)d_in[1];
  const float* wk   = (const float*)d_in[2];
  const float* wv   = (const float*)d_in[3];
  const float* wo   = (const float*)d_in[4];
  const float* qw   = (const float*)d_in[5];
  const float* kw   = (const float*)d_in[6];
  const float* cosb = (const float*)d_in[7];
  const float* sinb = (const float*)d_in[8];

  u16* xb   = (u16*)d_ws;                    // [2048][2048]
  u16* wqb  = xb  + (size_t)2048 * 2048;     // [4096][2048]
  u16* wkvb = wqb + (size_t)4096 * 2048;     // [1024][2048]
  u16* wob  = wkvb + (size_t)1024 * 2048;    // [2048][4096]
  u16* qbuf = wob + (size_t)2048 * 4096;     // [2048][4096]
  u16* kvb  = qbuf + (size_t)2048 * 4096;    // [2048][1024]
  u16* vt   = kvb + (size_t)2048 * 1024;     // [512][2048]
  u16* aout = vt  + (size_t)512 * 2048;      // [2048][4096]

  // 1. converts
  k_cvt<<<dim3(4096), 256, 0, stream>>>(x,  xb,   2048 * 2048 / 4);
  k_cvt<<<dim3(8192), 256, 0, stream>>>(wq, wqb,  4096 * 2048 / 4);
  k_cvt<<<dim3(1024), 256, 0, stream>>>(wk, wkvb,                      512 * 2048 / 4);
  k_cvt<<<dim3(1024), 256, 0, stream>>>(wv, wkvb + (size_t)512 * 2048, 512 * 2048 / 4);
  k_cvt<<<dim3(8192), 256, 0, stream>>>(wo, wob,  2048 * 4096 / 4);

  // 2. fused Q + KV projection
  k_gemm<2048, false, 4, true><<<dim3(16, 40), 256, 0, stream>>>(
      xb, wqb, wkvb, qbuf, kvb, 4096, 1024, 32);

  // 3. rmsnorm + rope (+ Q pre-scale)
  k_normrope<<<dim3((2048 * 36) / 4), 256, 0, stream>>>(qbuf, kvb, qw, kw, cosb, sinb);

  // 4. V transpose (chunk-permuted)
  k_transpose_v<<<dim3(64, 16), 256, 0, stream>>>(kvb, vt);

  // 5. flash attention
  k_attn<<<dim3(512), 512, 0, stream>>>(qbuf, kvb, vt, aout);

  // 6. output projection
  k_gemm<4096, true, 2, false><<<dim3(16, 32), 256, 0, stream>>>(
      aout, wob, nullptr, d_out, nullptr, 2048, 0, 0);
}

// Round 4
// 217.201 us; speedup vs baseline: 1.6758x; 1.1029x over previous
//
#include <hip/hip_runtime.h>

typedef unsigned short u16;
typedef short bh8 __attribute__((ext_vector_type(8)));
typedef short bh4 __attribute__((ext_vector_type(4)));
typedef float f4 __attribute__((ext_vector_type(4)));
typedef u16 u16x4 __attribute__((ext_vector_type(4)));

// ---------- helpers ----------
__device__ __forceinline__ u16 f2bf(float f) {
  union { float f; unsigned u; } v; v.f = f;
  unsigned u = v.u;
  return (u16)((u + 0x7fffu + ((u >> 16) & 1u)) >> 16);   // RNE, finite inputs
}
__device__ __forceinline__ float bf2f(u16 h) {
  union { unsigned u; float f; } v; v.u = ((unsigned)h) << 16;
  return v.f;
}
__device__ __forceinline__ void gll16(const void* src, void* dst) {
  __builtin_amdgcn_global_load_lds((const __attribute__((address_space(1))) void*)src,
                                   (__attribute__((address_space(3))) void*)dst,
                                   16, 0, 0);
}

// ---------- fused f32 -> bf16 convert of all 5 tensors (contiguous ws dst) ----------
__global__ __launch_bounds__(256) void k_cvt_all(const float* __restrict__ x,
                                                 const float* __restrict__ wq,
                                                 const float* __restrict__ wk,
                                                 const float* __restrict__ wv,
                                                 const float* __restrict__ wo,
                                                 u16* __restrict__ dst) {
  const size_t n = 5767168;   // total float4 count (x 1M, wq 2M, wk 256K, wv 256K, wo 2M)
  for (size_t idx = (size_t)blockIdx.x * 256 + threadIdx.x; idx < n; idx += 4096ull * 256) {
    const float* src; size_t off;
    if (idx < 1048576)       { src = x;  off = idx; }
    else if (idx < 3145728)  { src = wq; off = idx - 1048576; }
    else if (idx < 3407872)  { src = wk; off = idx - 3145728; }
    else if (idx < 3670016)  { src = wv; off = idx - 3407872; }
    else                     { src = wo; off = idx - 3670016; }
    f4 v = *(const f4*)(src + off * 4);
    u16x4 o;
    o.x = f2bf(v[0]); o.y = f2bf(v[1]); o.z = f2bf(v[2]); o.w = f2bf(v[3]);
    *(u16x4*)(dst + idx * 4) = o;
  }
}

// ---------- NT GEMM, depth-2 counted-vmcnt pipeline: C[M,N] = A[M,K] * B[N,K]^T ----------
// 128xBN tile (BN = NFR*32), BK=32, 4 waves (2x2), 3 LDS buffers, raw barriers,
// s_waitcnt vmcnt(2L) in steady state (never 0 until the tail).  XCD-swizzled 1D grid.
template<int K, bool OUTF32, int NFR, bool FUSED>
__global__ __launch_bounds__(256) void k_gemm(const u16* __restrict__ A,
                                              const u16* __restrict__ B1,
                                              const u16* __restrict__ B2,
                                              void* __restrict__ C1,
                                              void* __restrict__ C2,
                                              int N1, int N2, int NB1, int npx) {
  constexpr int BN = NFR * 32;
  constexpr int nk = K / 32;
  __shared__ u16 As[3][128 * 32];
  __shared__ u16 Bs[3][BN * 32];
  const int t = threadIdx.x;
  const int lane = t & 63;
  const int w = t >> 6, wm = w >> 1, wn = w & 1;
  const int g = lane >> 4, r16 = lane & 15;
  const int bb = blockIdx.x;
  const int gl = (bb & 7) * npx + (bb >> 3);      // XCD-contiguous mapping
  const int bm = gl & 15;
  int bn = gl >> 4;

  const u16* B; void* C; int N;
  if (!FUSED || bn < NB1) { B = B1; C = C1; N = N1; }
  else { bn -= NB1; B = B2; C = C2; N = N2; }
  B += (size_t)bn * BN * K;

  f4 acc[4][NFR] = {};

  const int rA0 = t >> 2, cA0 = (t & 3) * 8;
  const u16* a0 = A + (size_t)(bm * 128 + rA0) * K + cA0;
  const u16* a1 = a0 + (size_t)64 * K;
  const u16* b0 = B + (size_t)rA0 * K + cA0;

  auto STAGE = [&](int kk, int bi) {
    gll16(a0 + kk * 32, As[bi] + t * 8);
    gll16(a1 + kk * 32, As[bi] + (t + 256) * 8);
    gll16(b0 + kk * 32, Bs[bi] + t * 8);
    if constexpr (BN == 128) gll16(b0 + (size_t)64 * K + kk * 32, Bs[bi] + (t + 256) * 8);
  };
  auto COMP = [&](int bi) {
    bh8 af[4], bfr[NFR];
#pragma unroll
    for (int m = 0; m < 4; ++m)
      af[m] = *(const bh8*)&As[bi][(wm * 64 + m * 16 + r16) * 32 + g * 8];
#pragma unroll
    for (int n = 0; n < NFR; ++n)
      bfr[n] = *(const bh8*)&Bs[bi][(wn * 16 * NFR + n * 16 + r16) * 32 + g * 8];
    __builtin_amdgcn_s_setprio(1);
#pragma unroll
    for (int m = 0; m < 4; ++m)
#pragma unroll
      for (int n = 0; n < NFR; ++n)
        acc[m][n] = __builtin_amdgcn_mfma_f32_16x16x32_bf16(af[m], bfr[n], acc[m][n], 0, 0, 0);
    __builtin_amdgcn_s_setprio(0);
  };

  STAGE(0, 0);
  STAGE(1, 1);

  int bi = 0;
  for (int k = 0; k < nk - 2; ++k) {
    int st = bi + 2; if (st >= 3) st -= 3;
    STAGE(k + 2, st);
    if constexpr (BN == 128) asm volatile("s_waitcnt vmcnt(8)" ::: "memory");
    else                     asm volatile("s_waitcnt vmcnt(6)" ::: "memory");
    __builtin_amdgcn_s_barrier();
    __builtin_amdgcn_sched_barrier(0);
    COMP(bi);
    asm volatile("s_waitcnt lgkmcnt(0)" ::: "memory");
    __builtin_amdgcn_s_barrier();
    bi = (bi + 1 == 3) ? 0 : bi + 1;
  }
  // k = nk-2: one stage still in flight
  if constexpr (BN == 128) asm volatile("s_waitcnt vmcnt(4)" ::: "memory");
  else                     asm volatile("s_waitcnt vmcnt(3)" ::: "memory");
  __builtin_amdgcn_s_barrier();
  __builtin_amdgcn_sched_barrier(0);
  COMP(bi);
  asm volatile("s_waitcnt lgkmcnt(0)" ::: "memory");
  __builtin_amdgcn_s_barrier();
  bi = (bi + 1 == 3) ? 0 : bi + 1;
  // k = nk-1: drain
  asm volatile("s_waitcnt vmcnt(0)" ::: "memory");
  __builtin_amdgcn_s_barrier();
  __builtin_amdgcn_sched_barrier(0);
  COMP(bi);

#pragma unroll
  for (int m = 0; m < 4; ++m) {
    const int row0 = bm * 128 + wm * 64 + m * 16 + g * 4;
#pragma unroll
    for (int n = 0; n < NFR; ++n) {
      const int col = bn * BN + wn * 16 * NFR + n * 16 + r16;
#pragma unroll
      for (int r = 0; r < 4; ++r) {
        if constexpr (OUTF32)
          ((float*)C)[(size_t)(row0 + r) * N + col] = acc[m][n][r];
        else
          ((u16*)C)[(size_t)(row0 + r) * N + col] = f2bf(acc[m][n][r]);
      }
    }
  }
}

// ---------- fused RMSNorm + RoPE (in-place on bf16 Q / K buffers) ----------
__global__ __launch_bounds__(256) void k_normrope(u16* __restrict__ qbuf,
                                                  u16* __restrict__ kvbuf,
                                                  const float* __restrict__ qw,
                                                  const float* __restrict__ kw,
                                                  const float* __restrict__ cosb,
                                                  const float* __restrict__ sinb) {
  const float CSC = 1.4426950408889634f * 0.088388347648318447f;  // log2(e)/sqrt(128)
  const int t = threadIdx.x, lane = t & 63, w = t >> 6;
  const int rid = blockIdx.x * 4 + w;
  u16* base; const float* nw; int seq; float sc;
  if (rid < 2048 * 32) {
    seq = rid >> 5;
    base = qbuf + (size_t)seq * 4096 + (size_t)(rid & 31) * 128;
    nw = qw; sc = CSC;
  } else {
    const int r2 = rid - 2048 * 32;
    seq = r2 >> 2;
    base = kvbuf + (size_t)seq * 1024 + (size_t)(r2 & 3) * 128;
    nw = kw; sc = 1.0f;
  }
  float a = bf2f(base[lane]);
  float b = bf2f(base[lane + 64]);
  float ss = a * a + b * b;
#pragma unroll
  for (int off = 32; off >= 1; off >>= 1) ss += __shfl_xor(ss, off);
  const float rs = rsqrtf(ss * (1.0f / 128.0f) + 1e-6f);
  const float na = a * rs * nw[lane];
  const float nb = b * rs * nw[lane + 64];
  const float c1 = cosb[seq * 128 + lane],      s1 = sinb[seq * 128 + lane];
  const float c2 = cosb[seq * 128 + lane + 64], s2 = sinb[seq * 128 + lane + 64];
  base[lane]      = f2bf(sc * (c1 * na - s1 * nb));
  base[lane + 64] = f2bf(sc * (c2 * nb + s2 * na));
}

// ---------- V transpose: kv[:,512+hd] -> vt[hd][l], 32-key chunk permuted ----------
__global__ __launch_bounds__(256) void k_transpose_v(const u16* __restrict__ kv,
                                                     u16* __restrict__ vt) {
  __shared__ u16 tile[32][33];
  const int t = threadIdx.x;
  const int bl = blockIdx.x, bh = blockIdx.y;
  const int row = t >> 3, c4 = (t & 7) * 4;
  const u16* src = kv + (size_t)(bl * 32 + row) * 1024 + 512 + bh * 32 + c4;
  u16x4 v = *(const u16x4*)src;
  tile[row][c4 + 0] = v.x; tile[row][c4 + 1] = v.y;
  tile[row][c4 + 2] = v.z; tile[row][c4 + 3] = v.w;
  __syncthreads();
  u16x4 o;
  o.x = tile[c4 + 0][row]; o.y = tile[c4 + 1][row];
  o.z = tile[c4 + 2][row]; o.w = tile[c4 + 3][row];
  const int pcol = ((c4 >> 2) & 3) * 8 + (c4 >> 4) * 4;   // pi^-1
  *(u16x4*)&vt[(size_t)(bh * 32 + row) * 2048 + bl * 32 + pcol] = o;
}

// ---------- flash attention ----------
// 4 waves, 64 q-rows/block, KVBLK=64.  K double-buffered, V single-buffered
// (48KB LDS -> 3 blocks/CU).  1024 blocks, big q-tiles dispatched first, KV-head-
// aware XCD swizzle.  Swapped QK^T; PV on x32 with chunk-permuted V^T.
__global__ __launch_bounds__(256, 3) void k_attn(const u16* __restrict__ Q,
                                                 const u16* __restrict__ Kb,
                                                 const u16* __restrict__ Vt,
                                                 u16* __restrict__ O) {
  __shared__ u16 Ks[2][64 * 128];   // 32 KB
  __shared__ u16 Vs[128 * 64];      // 16 KB
  const int t = threadIdx.x, lane = t & 63, w = t >> 6;
  const int g = lane >> 4, r16 = lane & 15;
  const int b = blockIdx.x;
  const int i = b & 31;
  const int qt = 31 - (b >> 5);                       // big tiles first
  const int h = ((i >> 1) & 3) * 8 + ((i & 1) << 2) + (i >> 3);  // same-kvh heads share XCD
  const int kvh = h >> 3;
  const int qw0 = qt * 64 + w * 16;
  const int qg  = qw0 + r16;

  bh8 qf[4];
#pragma unroll
  for (int kc = 0; kc < 4; ++kc)
    qf[kc] = *(const bh8*)(Q + (size_t)qg * 4096 + h * 128 + (kc * 4 + g) * 8);

  const int niter = qt + 1;

  f4 acc_o[8] = {};
  float mrun = -3.0e38f, lsum = 0.0f;

  // prologue: stage K[0] into Ks[0]
#pragma unroll
  for (int i2 = 0; i2 < 4; ++i2) {
    const int s = t + 256 * i2, row = s >> 4, sl = s & 15;
    gll16(Kb + (size_t)row * 1024 + kvh * 128 + ((sl ^ (row & 15)) * 8), Ks[0] + s * 8);
  }
  __syncthreads();

  int cur = 0;
  for (int kt = 0; kt < niter; ++kt) {
    // stage V[kt] (read after mid-iter barrier) and prefetch K[kt+1]
#pragma unroll
    for (int i2 = 0; i2 < 4; ++i2) {
      const int s = t + 256 * i2, row = s >> 3, sl = s & 7;
      gll16(Vt + (size_t)(kvh * 128 + row) * 2048 + kt * 64 + ((sl ^ (row & 7)) * 8),
            Vs + s * 8);
    }
    if (kt + 1 < niter) {
      const int nt = kt + 1;
#pragma unroll
      for (int i2 = 0; i2 < 4; ++i2) {
        const int s = t + 256 * i2, row = s >> 4, sl = s & 15;
        gll16(Kb + (size_t)(nt * 64 + row) * 1024 + kvh * 128 + ((sl ^ (row & 15)) * 8),
              Ks[cur ^ 1] + s * 8);
      }
    }

    // QK^T (swapped operands -> S^T), scores in log2 domain
    f4 st[4] = {};
    __builtin_amdgcn_s_setprio(1);
#pragma unroll
    for (int kf = 0; kf < 4; ++kf) {
      const int krow = kf * 16 + r16;
#pragma unroll
      for (int kc = 0; kc < 4; ++kc) {
        bh8 kfr = *(const bh8*)&Ks[cur][krow * 128 + (((kc * 4 + g) ^ (krow & 15)) * 8)];
        st[kf] = __builtin_amdgcn_mfma_f32_16x16x32_bf16(kfr, qf[kc], st[kf], 0, 0, 0);
      }
    }
    __builtin_amdgcn_s_setprio(0);

    float tmax = -3.0e38f;
    const bool edge = ((kt + 1) * 64 - 1 > qw0);
#pragma unroll
    for (int kf = 0; kf < 4; ++kf)
#pragma unroll
      for (int r = 0; r < 4; ++r) {
        float v = st[kf][r];
        if (edge && (kt * 64 + kf * 16 + g * 4 + r) > qg) v = -3.0e38f;
        st[kf][r] = v;
        tmax = fmaxf(tmax, v);
      }
    tmax = fmaxf(tmax, __shfl_xor(tmax, 16));
    tmax = fmaxf(tmax, __shfl_xor(tmax, 32));

    if (!__all(tmax <= mrun + 8.0f)) {       // defer-max (T13)
      const float mnew = fmaxf(mrun, tmax);
      const float alpha = exp2f(mrun - mnew);
      mrun = mnew;
      lsum *= alpha;
#pragma unroll
      for (int d = 0; d < 8; ++d) acc_o[d] *= alpha;
    }

    float psum = 0.0f;
    bh8 pb2[2];
#pragma unroll
    for (int kf = 0; kf < 4; ++kf)
#pragma unroll
      for (int r = 0; r < 4; ++r) {
        float p = exp2f(st[kf][r] - mrun);
        psum += p;
        pb2[kf >> 1][(kf & 1) * 4 + r] = (short)f2bf(p);
      }
    psum += __shfl_xor(psum, 16);
    psum += __shfl_xor(psum, 32);
    lsum += psum;

    __syncthreads();   // drains V[kt] (and K[kt+1]) stages; all QK^T reads of Ks[cur] done

    // O^T += V^T * P^T on x32 (chunk-permuted V^T matches P^T k-slots)
    __builtin_amdgcn_s_setprio(1);
#pragma unroll
    for (int dcol = 0; dcol < 8; ++dcol) {
      const int vrow = dcol * 16 + r16;
#pragma unroll
      for (int c = 0; c < 2; ++c) {
        const int slot = c * 4 + g;
        bh8 vfr = *(const bh8*)&Vs[vrow * 64 + ((slot ^ (vrow & 7)) * 8)];
        acc_o[dcol] = __builtin_amdgcn_mfma_f32_16x16x32_bf16(vfr, pb2[c], acc_o[dcol], 0, 0, 0);
      }
    }
    __builtin_amdgcn_s_setprio(0);

    __syncthreads();   // all PV reads of Vs done before next iter's V stage
    cur ^= 1;
  }

  const float inv = 1.0f / lsum;
#pragma unroll
  for (int dcol = 0; dcol < 8; ++dcol) {
    u16x4 o;
    o.x = f2bf(acc_o[dcol][0] * inv);
    o.y = f2bf(acc_o[dcol][1] * inv);
    o.z = f2bf(acc_o[dcol][2] * inv);
    o.w = f2bf(acc_o[dcol][3] * inv);
    *(u16x4*)&O[(size_t)qg * 4096 + h * 128 + dcol * 16 + g * 4] = o;
  }
}

// ---------- launch ----------
extern "C" void kernel_launch(void* const* d_in, const int* in_sizes, int n_in,
                              void* d_out, int out_size, void* d_ws, size_t ws_size,
                              hipStream_t stream) {
  (void)in_sizes; (void)n_in; (void)out_size; (void)ws_size;
  const float* x    = (const float*)d_in[0];
  const float* wq   = (const float*)d_in[1];
  const float* wk   = (const float*)d_in[2];
  const float* wv   = (const float*)d_in[3];
  const float* wo   = (const float*)d_in[4];
  const float* qw   = (const float*)d_in[5];
  const float* kw   = (const float*)d_in[6];
  const float* cosb = (const float*)d_in[7];
  const float* sinb = (const float*)d_in[8];

  u16* xb   = (u16*)d_ws;                    // [2048][2048]
  u16* wqb  = xb  + (size_t)2048 * 2048;     // [4096][2048]
  u16* wkvb = wqb + (size_t)4096 * 2048;     // [1024][2048]  (wk rows, then wv rows)
  u16* wob  = wkvb + (size_t)1024 * 2048;    // [2048][4096]
  u16* qbuf = wob + (size_t)2048 * 4096;     // [2048][4096]
  u16* kvb  = qbuf + (size_t)2048 * 4096;    // [2048][1024]
  u16* vt   = kvb + (size_t)2048 * 1024;     // [512][2048]
  u16* aout = vt  + (size_t)512 * 2048;      // [2048][4096]

  // 1. fused converts (x|wq|wk|wv|wo -> contiguous bf16 ws region)
  k_cvt_all<<<dim3(4096), 256, 0, stream>>>(x, wq, wk, wv, wo, xb);

  // 2. fused Q + KV projection (640 blocks, XCD-swizzled)
  k_gemm<2048, false, 4, true><<<dim3(640), 256, 0, stream>>>(
      xb, wqb, wkvb, qbuf, kvb, 4096, 1024, 32, 80);

  // 3. rmsnorm + rope (+ Q pre-scale)
  k_normrope<<<dim3((2048 * 36) / 4), 256, 0, stream>>>(qbuf, kvb, qw, kw, cosb, sinb);

  // 4. V transpose (chunk-permuted)
  k_transpose_v<<<dim3(64, 16), 256, 0, stream>>>(kvb, vt);

  // 5. flash attention (1024 balanced blocks, 3/CU)
  k_attn<<<dim3(1024), 256, 0, stream>>>(qbuf, kvb, vt, aout);

  // 6. output projection (512 blocks, XCD-swizzled)
  k_gemm<4096, true, 2, false><<<dim3(512), 256, 0, stream>>>(
      aout, wob, nullptr, d_out, nullptr, 2048, 0, 0, 64);
}

// Round 5
// 208.269 us; speedup vs baseline: 1.7477x; 1.0429x over previous
//
#include <hip/hip_runtime.h>

typedef unsigned short u16;
typedef short bh8 __attribute__((ext_vector_type(8)));
typedef short bh4 __attribute__((ext_vector_type(4)));
typedef float f4 __attribute__((ext_vector_type(4)));
typedef u16 u16x4 __attribute__((ext_vector_type(4)));

// ---------- helpers ----------
__device__ __forceinline__ u16 f2bf(float f) {
  union { float f; unsigned u; } v; v.f = f;
  unsigned u = v.u;
  return (u16)((u + 0x7fffu + ((u >> 16) & 1u)) >> 16);   // RNE, finite inputs
}
__device__ __forceinline__ float bf2f(u16 h) {
  union { unsigned u; float f; } v; v.u = ((unsigned)h) << 16;
  return v.f;
}
__device__ __forceinline__ float fast_exp2(float x) {
#if __has_builtin(__builtin_amdgcn_exp2f)
  return __builtin_amdgcn_exp2f(x);
#else
  float r; asm("v_exp_f32 %0, %1" : "=v"(r) : "v"(x)); return r;
#endif
}
__device__ __forceinline__ unsigned cvt_pk_bf16(float lo, float hi) {
  unsigned r;
  asm("v_cvt_pk_bf16_f32 %0, %1, %2" : "=v"(r) : "v"(lo), "v"(hi));
  return r;
}
__device__ __forceinline__ void gll16(const void* src, void* dst) {
  __builtin_amdgcn_global_load_lds((const __attribute__((address_space(1))) void*)src,
                                   (__attribute__((address_space(3))) void*)dst,
                                   16, 0, 0);
}

// ---------- fused f32 -> bf16 convert of all 5 tensors (contiguous ws dst) ----------
__global__ __launch_bounds__(256) void k_cvt_all(const float* __restrict__ x,
                                                 const float* __restrict__ wq,
                                                 const float* __restrict__ wk,
                                                 const float* __restrict__ wv,
                                                 const float* __restrict__ wo,
                                                 u16* __restrict__ dst) {
  const size_t n = 5767168;   // total float4 count
  for (size_t idx = (size_t)blockIdx.x * 256 + threadIdx.x; idx < n; idx += 4096ull * 256) {
    const float* src; size_t off;
    if (idx < 1048576)       { src = x;  off = idx; }
    else if (idx < 3145728)  { src = wq; off = idx - 1048576; }
    else if (idx < 3407872)  { src = wk; off = idx - 3145728; }
    else if (idx < 3670016)  { src = wv; off = idx - 3407872; }
    else                     { src = wo; off = idx - 3670016; }
    f4 v = *(const f4*)(src + off * 4);
    u16x4 o;
    o.x = f2bf(v[0]); o.y = f2bf(v[1]); o.z = f2bf(v[2]); o.w = f2bf(v[3]);
    *(u16x4*)(dst + idx * 4) = o;
  }
}

// ---------- NT GEMM, depth-2 counted-vmcnt pipeline: C[M,N] = A[M,K] * B[N,K]^T ----------
template<int K, bool OUTF32, int NFR, bool FUSED>
__global__ __launch_bounds__(256) void k_gemm(const u16* __restrict__ A,
                                              const u16* __restrict__ B1,
                                              const u16* __restrict__ B2,
                                              void* __restrict__ C1,
                                              void* __restrict__ C2,
                                              int N1, int N2, int NB1, int npx) {
  constexpr int BN = NFR * 32;
  constexpr int nk = K / 32;
  __shared__ u16 As[3][128 * 32];
  __shared__ u16 Bs[3][BN * 32];
  const int t = threadIdx.x;
  const int lane = t & 63;
  const int w = t >> 6, wm = w >> 1, wn = w & 1;
  const int g = lane >> 4, r16 = lane & 15;
  const int bb = blockIdx.x;
  const int gl = (bb & 7) * npx + (bb >> 3);      // XCD-contiguous mapping
  const int bm = gl & 15;
  int bn = gl >> 4;

  const u16* B; void* C; int N;
  if (!FUSED || bn < NB1) { B = B1; C = C1; N = N1; }
  else { bn -= NB1; B = B2; C = C2; N = N2; }
  B += (size_t)bn * BN * K;

  f4 acc[4][NFR] = {};

  const int rA0 = t >> 2, cA0 = (t & 3) * 8;
  const u16* a0 = A + (size_t)(bm * 128 + rA0) * K + cA0;
  const u16* a1 = a0 + (size_t)64 * K;
  const u16* b0 = B + (size_t)rA0 * K + cA0;

  auto STAGE = [&](int kk, int bi) {
    gll16(a0 + kk * 32, As[bi] + t * 8);
    gll16(a1 + kk * 32, As[bi] + (t + 256) * 8);
    gll16(b0 + kk * 32, Bs[bi] + t * 8);
    if constexpr (BN == 128) gll16(b0 + (size_t)64 * K + kk * 32, Bs[bi] + (t + 256) * 8);
  };
  auto COMP = [&](int bi) {
    bh8 af[4], bfr[NFR];
#pragma unroll
    for (int m = 0; m < 4; ++m)
      af[m] = *(const bh8*)&As[bi][(wm * 64 + m * 16 + r16) * 32 + g * 8];
#pragma unroll
    for (int n = 0; n < NFR; ++n)
      bfr[n] = *(const bh8*)&Bs[bi][(wn * 16 * NFR + n * 16 + r16) * 32 + g * 8];
    __builtin_amdgcn_s_setprio(1);
#pragma unroll
    for (int m = 0; m < 4; ++m)
#pragma unroll
      for (int n = 0; n < NFR; ++n)
        acc[m][n] = __builtin_amdgcn_mfma_f32_16x16x32_bf16(af[m], bfr[n], acc[m][n], 0, 0, 0);
    __builtin_amdgcn_s_setprio(0);
  };

  STAGE(0, 0);
  STAGE(1, 1);

  int bi = 0;
  for (int k = 0; k < nk - 2; ++k) {
    int st = bi + 2; if (st >= 3) st -= 3;
    STAGE(k + 2, st);
    if constexpr (BN == 128) asm volatile("s_waitcnt vmcnt(8)" ::: "memory");
    else                     asm volatile("s_waitcnt vmcnt(6)" ::: "memory");
    __builtin_amdgcn_s_barrier();
    __builtin_amdgcn_sched_barrier(0);
    COMP(bi);
    asm volatile("s_waitcnt lgkmcnt(0)" ::: "memory");
    __builtin_amdgcn_s_barrier();
    bi = (bi + 1 == 3) ? 0 : bi + 1;
  }
  if constexpr (BN == 128) asm volatile("s_waitcnt vmcnt(4)" ::: "memory");
  else                     asm volatile("s_waitcnt vmcnt(3)" ::: "memory");
  __builtin_amdgcn_s_barrier();
  __builtin_amdgcn_sched_barrier(0);
  COMP(bi);
  asm volatile("s_waitcnt lgkmcnt(0)" ::: "memory");
  __builtin_amdgcn_s_barrier();
  bi = (bi + 1 == 3) ? 0 : bi + 1;
  asm volatile("s_waitcnt vmcnt(0)" ::: "memory");
  __builtin_amdgcn_s_barrier();
  __builtin_amdgcn_sched_barrier(0);
  COMP(bi);

#pragma unroll
  for (int m = 0; m < 4; ++m) {
    const int row0 = bm * 128 + wm * 64 + m * 16 + g * 4;
#pragma unroll
    for (int n = 0; n < NFR; ++n) {
      const int col = bn * BN + wn * 16 * NFR + n * 16 + r16;
#pragma unroll
      for (int r = 0; r < 4; ++r) {
        if constexpr (OUTF32)
          ((float*)C)[(size_t)(row0 + r) * N + col] = acc[m][n][r];
        else
          ((u16*)C)[(size_t)(row0 + r) * N + col] = f2bf(acc[m][n][r]);
      }
    }
  }
}

// ---------- fused RMSNorm + RoPE (in-place on bf16 Q / K buffers) ----------
__global__ __launch_bounds__(256) void k_normrope(u16* __restrict__ qbuf,
                                                  u16* __restrict__ kvbuf,
                                                  const float* __restrict__ qw,
                                                  const float* __restrict__ kw,
                                                  const float* __restrict__ cosb,
                                                  const float* __restrict__ sinb) {
  const float CSC = 1.4426950408889634f * 0.088388347648318447f;  // log2(e)/sqrt(128)
  const int t = threadIdx.x, lane = t & 63, w = t >> 6;
  const int rid = blockIdx.x * 4 + w;
  u16* base; const float* nw; int seq; float sc;
  if (rid < 2048 * 32) {
    seq = rid >> 5;
    base = qbuf + (size_t)seq * 4096 + (size_t)(rid & 31) * 128;
    nw = qw; sc = CSC;
  } else {
    const int r2 = rid - 2048 * 32;
    seq = r2 >> 2;
    base = kvbuf + (size_t)seq * 1024 + (size_t)(r2 & 3) * 128;
    nw = kw; sc = 1.0f;
  }
  float a = bf2f(base[lane]);
  float b = bf2f(base[lane + 64]);
  float ss = a * a + b * b;
#pragma unroll
  for (int off = 32; off >= 1; off >>= 1) ss += __shfl_xor(ss, off);
  const float rs = rsqrtf(ss * (1.0f / 128.0f) + 1e-6f);
  const float na = a * rs * nw[lane];
  const float nb = b * rs * nw[lane + 64];
  const float c1 = cosb[seq * 128 + lane],      s1 = sinb[seq * 128 + lane];
  const float c2 = cosb[seq * 128 + lane + 64], s2 = sinb[seq * 128 + lane + 64];
  base[lane]      = f2bf(sc * (c1 * na - s1 * nb));
  base[lane + 64] = f2bf(sc * (c2 * nb + s2 * na));
}

// ---------- V transpose: kv[:,512+hd] -> vt[hd][l], 32-key chunk permuted ----------
__global__ __launch_bounds__(256) void k_transpose_v(const u16* __restrict__ kv,
                                                     u16* __restrict__ vt) {
  __shared__ u16 tile[32][33];
  const int t = threadIdx.x;
  const int bl = blockIdx.x, bh = blockIdx.y;
  const int row = t >> 3, c4 = (t & 7) * 4;
  const u16* src = kv + (size_t)(bl * 32 + row) * 1024 + 512 + bh * 32 + c4;
  u16x4 v = *(const u16x4*)src;
  tile[row][c4 + 0] = v.x; tile[row][c4 + 1] = v.y;
  tile[row][c4 + 2] = v.z; tile[row][c4 + 3] = v.w;
  __syncthreads();
  u16x4 o;
  o.x = tile[c4 + 0][row]; o.y = tile[c4 + 1][row];
  o.z = tile[c4 + 2][row]; o.w = tile[c4 + 3][row];
  const int pcol = ((c4 >> 2) & 3) * 8 + (c4 >> 4) * 4;   // pi^-1
  *(u16x4*)&vt[(size_t)(bh * 32 + row) * 2048 + bl * 32 + pcol] = o;
}

// ---------- flash attention ----------
// 4 waves, 64 q-rows/block, KVBLK=64.  K dbuf + V single-buffered (48KB LDS).
// Swapped QK^T (log2-domain scores via Q pre-scale); PV on x32 with chunk-
// permuted V^T; lsum via ones-MFMA; raw v_exp_f32; cvt_pk bf16 packs.
__global__ __launch_bounds__(256, 3) void k_attn(const u16* __restrict__ Q,
                                                 const u16* __restrict__ Kb,
                                                 const u16* __restrict__ Vt,
                                                 u16* __restrict__ O) {
  __shared__ u16 Ks[2][64 * 128];   // 32 KB
  __shared__ u16 Vs[128 * 64];      // 16 KB
  const int t = threadIdx.x, lane = t & 63, w = t >> 6;
  const int g = lane >> 4, r16 = lane & 15;
  const int b = blockIdx.x;
  const int i = b & 31;
  const int qt = 31 - (b >> 5);                       // big tiles first
  const int h = ((i >> 1) & 3) * 8 + ((i & 1) << 2) + (i >> 3);
  const int kvh = h >> 3;
  const int qw0 = qt * 64 + w * 16;
  const int qg  = qw0 + r16;

  bh8 qf[4];
#pragma unroll
  for (int kc = 0; kc < 4; ++kc)
    qf[kc] = *(const bh8*)(Q + (size_t)qg * 4096 + h * 128 + (kc * 4 + g) * 8);

  const int niter = qt + 1;

  f4 acc_o[8] = {};
  f4 acc_l = {};                     // lsum via ones-MFMA (all 4 elems identical)
  float mrun = -3.0e38f;

  bh8 ones;
#pragma unroll
  for (int z = 0; z < 8; ++z) ones[z] = (short)0x3F80;   // 1.0bf16

  // prologue: stage K[0]
#pragma unroll
  for (int i2 = 0; i2 < 4; ++i2) {
    const int s = t + 256 * i2, row = s >> 4, sl = s & 15;
    gll16(Kb + (size_t)row * 1024 + kvh * 128 + ((sl ^ (row & 15)) * 8), Ks[0] + s * 8);
  }
  __syncthreads();

  int cur = 0;
  for (int kt = 0; kt < niter; ++kt) {
    // stage V[kt]; prefetch K[kt+1]
#pragma unroll
    for (int i2 = 0; i2 < 4; ++i2) {
      const int s = t + 256 * i2, row = s >> 3, sl = s & 7;
      gll16(Vt + (size_t)(kvh * 128 + row) * 2048 + kt * 64 + ((sl ^ (row & 7)) * 8),
            Vs + s * 8);
    }
    if (kt + 1 < niter) {
      const int nt = kt + 1;
#pragma unroll
      for (int i2 = 0; i2 < 4; ++i2) {
        const int s = t + 256 * i2, row = s >> 4, sl = s & 15;
        gll16(Kb + (size_t)(nt * 64 + row) * 1024 + kvh * 128 + ((sl ^ (row & 15)) * 8),
              Ks[cur ^ 1] + s * 8);
      }
    }

    // QK^T (swapped operands -> S^T), scores in log2 domain
    f4 st[4] = {};
    __builtin_amdgcn_s_setprio(1);
#pragma unroll
    for (int kf = 0; kf < 4; ++kf) {
      const int krow = kf * 16 + r16;
#pragma unroll
      for (int kc = 0; kc < 4; ++kc) {
        bh8 kfr = *(const bh8*)&Ks[cur][krow * 128 + (((kc * 4 + g) ^ (krow & 15)) * 8)];
        st[kf] = __builtin_amdgcn_mfma_f32_16x16x32_bf16(kfr, qf[kc], st[kf], 0, 0, 0);
      }
    }
    __builtin_amdgcn_s_setprio(0);

    // causal mask only on the edge tile (block-uniform branch)
    if (kt == qt) {
      const int kb = kt * 64 + g * 4;
#pragma unroll
      for (int kf = 0; kf < 4; ++kf)
#pragma unroll
        for (int r = 0; r < 4; ++r)
          if (kb + kf * 16 + r > qg) st[kf][r] = -3.0e38f;
    }

    // row max: vector tree then cross-lane over the 4 g-groups
    f4 m4;
#pragma unroll
    for (int r = 0; r < 4; ++r)
      m4[r] = fmaxf(fmaxf(st[0][r], st[1][r]), fmaxf(st[2][r], st[3][r]));
    float tmax = fmaxf(fmaxf(m4[0], m4[1]), fmaxf(m4[2], m4[3]));
    tmax = fmaxf(tmax, __shfl_xor(tmax, 16));
    tmax = fmaxf(tmax, __shfl_xor(tmax, 32));

    if (!__all(tmax <= mrun + 8.0f)) {       // defer-max (T13)
      const float mnew = fmaxf(mrun, tmax);
      const float alpha = fast_exp2(mrun - mnew);
      mrun = mnew;
      acc_l *= alpha;
#pragma unroll
      for (int d = 0; d < 8; ++d) acc_o[d] *= alpha;
    }

    // P = exp2(S - m), packed to bf16 via v_cvt_pk
    union { bh8 v[2]; unsigned wrd[8]; } pu;
#pragma unroll
    for (int j = 0; j < 8; ++j) {
      const int i0 = 2 * j, i1 = 2 * j + 1;
      float p0 = fast_exp2(st[i0 >> 2][i0 & 3] - mrun);
      float p1 = fast_exp2(st[i1 >> 2][i1 & 3] - mrun);
      pu.wrd[j] = cvt_pk_bf16(p0, p1);
    }

    __syncthreads();   // V[kt] staged; all QK^T reads of Ks[cur] done

    // O^T += V^T * P^T ; lsum += ones * P^T
    __builtin_amdgcn_s_setprio(1);
#pragma unroll
    for (int c = 0; c < 2; ++c)
      acc_l = __builtin_amdgcn_mfma_f32_16x16x32_bf16(ones, pu.v[c], acc_l, 0, 0, 0);
#pragma unroll
    for (int dcol = 0; dcol < 8; ++dcol) {
      const int vrow = dcol * 16 + r16;
#pragma unroll
      for (int c = 0; c < 2; ++c) {
        const int slot = c * 4 + g;
        bh8 vfr = *(const bh8*)&Vs[vrow * 64 + ((slot ^ (vrow & 7)) * 8)];
        acc_o[dcol] = __builtin_amdgcn_mfma_f32_16x16x32_bf16(vfr, pu.v[c], acc_o[dcol], 0, 0, 0);
      }
    }
    __builtin_amdgcn_s_setprio(0);

    __syncthreads();   // PV reads of Vs done before next iter's V stage
    cur ^= 1;
  }

  const float inv = 1.0f / acc_l[0];
#pragma unroll
  for (int dcol = 0; dcol < 8; ++dcol) {
    union { u16x4 v; unsigned wrd[2]; } o;
    o.wrd[0] = cvt_pk_bf16(acc_o[dcol][0] * inv, acc_o[dcol][1] * inv);
    o.wrd[1] = cvt_pk_bf16(acc_o[dcol][2] * inv, acc_o[dcol][3] * inv);
    *(u16x4*)&O[(size_t)qg * 4096 + h * 128 + dcol * 16 + g * 4] = o.v;
  }
}

// ---------- launch ----------
extern "C" void kernel_launch(void* const* d_in, const int* in_sizes, int n_in,
                              void* d_out, int out_size, void* d_ws, size_t ws_size,
                              hipStream_t stream) {
  (void)in_sizes; (void)n_in; (void)out_size; (void)ws_size;
  const float* x    = (const float*)d_in[0];
  const float* wq   = (const float*)d_in[1];
  const float* wk   = (const float*)d_in[2];
  const float* wv   = (const float*)d_in[3];
  const float* wo   = (const float*)d_in[4];
  const float* qw   = (const float*)d_in[5];
  const float* kw   = (const float*)d_in[6];
  const float* cosb = (const float*)d_in[7];
  const float* sinb = (const float*)d_in[8];

  u16* xb   = (u16*)d_ws;                    // [2048][2048]
  u16* wqb  = xb  + (size_t)2048 * 2048;     // [4096][2048]
  u16* wkvb = wqb + (size_t)4096 * 2048;     // [1024][2048]
  u16* wob  = wkvb + (size_t)1024 * 2048;    // [2048][4096]
  u16* qbuf = wob + (size_t)2048 * 4096;     // [2048][4096]
  u16* kvb  = qbuf + (size_t)2048 * 4096;    // [2048][1024]
  u16* vt   = kvb + (size_t)2048 * 1024;     // [512][2048]
  u16* aout = vt  + (size_t)512 * 2048;      // [2048][4096]

  // 1. fused converts
  k_cvt_all<<<dim3(4096), 256, 0, stream>>>(x, wq, wk, wv, wo, xb);

  // 2. fused Q + KV projection
  k_gemm<2048, false, 4, true><<<dim3(640), 256, 0, stream>>>(
      xb, wqb, wkvb, qbuf, kvb, 4096, 1024, 32, 80);

  // 3. rmsnorm + rope (+ Q pre-scale)
  k_normrope<<<dim3((2048 * 36) / 4), 256, 0, stream>>>(qbuf, kvb, qw, kw, cosb, sinb);

  // 4. V transpose (chunk-permuted)
  k_transpose_v<<<dim3(64, 16), 256, 0, stream>>>(kvb, vt);

  // 5. flash attention
  k_attn<<<dim3(1024), 256, 0, stream>>>(qbuf, kvb, vt, aout);

  // 6. output projection
  k_gemm<4096, true, 2, false><<<dim3(512), 256, 0, stream>>>(
      aout, wob, nullptr, d_out, nullptr, 2048, 0, 0, 64);
}